// Round 6
// baseline (11590.972 us; speedup 1.0000x reference)
//
#include <hip/hip_runtime.h>

// SNN forward, exact fixed-point int8 MFMA, single persistent kernel.
// Diagonal-wavefront over (layer,t); grid barrier between diagonals.
// Numerics identical to rounds 4/5 (passed): spikes exact in i8; W = 5
// balanced base-256 digits of round(w*2^40); x pre-digitized to round(x*2^36)
// (5 planes, all 50 steps); i32 MFMA accumulation exact; fp64 reconstruction;
// membrane state carried in REGISTERS (fixed tile ownership per block).
// No LDS: MFMA fragments are 16 contiguous bytes per lane -> load direct from
// global (L1/L2-resident; XCD-remapped so each XCD's W slice stays L2-hot).

typedef int int4v __attribute__((ext_vector_type(4)));

#define XSCALE 68719476736.0      // 2^36
#define WSCALE 1099511627776.0    // 2^40
#define NBLK   392

struct Params {
    const signed char* xs;        // [50][5][512][832]
    const signed char* Wd[4];     // 5 planes each, rows padded: 1024/1024/1024/64
    const float* bias[4];
    float* spk[4];
    float* mem[4];
    signed char* sb[3][2];        // spike i8 buffers [layer][t&1], [512][1024]
    unsigned* bar;                // [counter, sense]
};

// ---- W digit split: fp32 [Nreal][K] -> 5 planes [Npad][Kpad], zero-padded ----
__global__ void wsplit_i8(const float* __restrict__ W, signed char* __restrict__ out,
                          int Nreal, int Npad, int K, int Kpad)
{
    int idx = blockIdx.x * blockDim.x + threadIdx.x;
    int total = Npad * Kpad;
    if (idx >= total) return;
    int n = idx / Kpad, k = idx - n * Kpad;
    long long v = 0;
    if (n < Nreal && k < K) v = __double2ll_rn((double)W[(size_t)n * K + k] * WSCALE);
    size_t plane = (size_t)total;
#pragma unroll
    for (int p = 0; p < 4; ++p) {
        int d = (int)(v & 255); if (d > 127) d -= 256;
        out[p * plane + idx] = (signed char)d;
        v = (v - d) >> 8;
    }
    out[4 * plane + idx] = (signed char)v;
}

// ---- x digit split: [50][512][784] -> [50][5][512][832] ----
__global__ void xsplit_i8(const float* __restrict__ x, signed char* __restrict__ out)
{
    const int RK = 512 * 832;
    int idx = blockIdx.x * blockDim.x + threadIdx.x;
    if (idx >= 50 * RK) return;
    int t = idx / RK, rem = idx - t * RK;
    int row = rem / 832, k = rem - row * 832;
    long long v = 0;
    if (k < 784) v = __double2ll_rn((double)x[((size_t)t * 512 + row) * 784 + k] * XSCALE);
    signed char* o = out + (size_t)t * 5 * RK + (size_t)row * 832 + k;
#pragma unroll
    for (int p = 0; p < 4; ++p) {
        int d = (int)(v & 255); if (d > 127) d -= 256;
        o[(size_t)p * RK] = (signed char)d;
        v = (v - d) >> 8;
    }
    o[(size_t)4 * RK] = (signed char)v;
}

// ---- device-scope sense-reversal grid barrier ----
__device__ __forceinline__ void grid_barrier(unsigned* bar)
{
    __syncthreads();
    if (threadIdx.x == 0) {
        unsigned* cnt = bar;
        unsigned* sen = bar + 1;
        unsigned s0 = __hip_atomic_load(sen, __ATOMIC_RELAXED, __HIP_MEMORY_SCOPE_AGENT);
        unsigned a  = __hip_atomic_fetch_add(cnt, 1u, __ATOMIC_ACQ_REL, __HIP_MEMORY_SCOPE_AGENT);
        if (a == (unsigned)(NBLK - 1)) {
            __hip_atomic_store(cnt, 0u, __ATOMIC_RELAXED, __HIP_MEMORY_SCOPE_AGENT);
            __hip_atomic_fetch_add(sen, 1u, __ATOMIC_RELEASE, __HIP_MEMORY_SCOPE_AGENT);
        } else {
            while (__hip_atomic_load(sen, __ATOMIC_ACQUIRE, __HIP_MEMORY_SCOPE_AGENT) == s0)
                __builtin_amdgcn_s_sleep(2);
        }
    }
    __syncthreads();
}

// ---- one (layer,bm,bn) tile for one timestep, fragments direct from global ----
template<bool L0>
__device__ __forceinline__ void run_tile(
    const signed char* __restrict__ Ap,    // A planes (xs[t] or spike buffer)
    const signed char* __restrict__ Wp,    // 5 padded W planes
    const float* __restrict__ bias,
    float* __restrict__ spk, float* __restrict__ mem,
    signed char* __restrict__ spk_i8,
    size_t planeW, int N, int bm, int bn, bool has_prev, double (&ms)[2][4])
{
    constexpr int KP = L0 ? 832 : 1024;
    constexpr int NA = L0 ? 5 : 1;
    const size_t planeA = (size_t)512 * KP;

    const int tid = threadIdx.x;
    const int l  = tid & 63;
    const int w  = tid >> 6;           // 0..7
    const int wm = (w & 3) * 16;
    const int wn = (w >> 2) * 32;
    const int fr = l & 15;
    const int g  = l >> 4;             // 16B chunk select

    const signed char* arow  = Ap + (size_t)(bm + wm + fr) * KP + 16 * g;
    const signed char* wrow0 = Wp + (size_t)(bn + wn + fr) * KP + 16 * g;
    const signed char* wrow1 = wrow0 + (size_t)16 * KP;

    int4v acc[2][5];
#pragma unroll
    for (int t2 = 0; t2 < 2; ++t2)
#pragma unroll
        for (int s = 0; s < 5; ++s) acc[t2][s] = (int4v){0, 0, 0, 0};

#pragma unroll 2
    for (int kb = 0; kb < KP; kb += 64) {
        int4v af[NA];
#pragma unroll
        for (int p = 0; p < NA; ++p)
            af[p] = *(const int4v*)(arow + (size_t)p * planeA + kb);
#pragma unroll
        for (int t2 = 0; t2 < 2; ++t2) {
            const signed char* wr = t2 ? wrow1 : wrow0;
            if constexpr (L0) {
#pragma unroll
                for (int q = 0; q < 5; ++q) {
                    int4v bq = *(const int4v*)(wr + (size_t)q * planeW + kb);
#pragma unroll
                    for (int p = 0; p < 5; ++p)
                        if (p + q >= 4)
                            acc[t2][p + q - 4] = __builtin_amdgcn_mfma_i32_16x16x64_i8(
                                af[p], bq, acc[t2][p + q - 4], 0, 0, 0);
                }
            } else {
#pragma unroll
                for (int q = 0; q < 5; ++q) {
                    int4v bq = *(const int4v*)(wr + (size_t)q * planeW + kb);
                    acc[t2][q] = __builtin_amdgcn_mfma_i32_16x16x64_i8(
                        af[0], bq, acc[t2][q], 0, 0, 0);
                }
            }
        }
    }

    // epilogue: fp64 reconstruction + leaky-IF; C/D: col=l&15, row=4*(l>>4)+r
#pragma unroll
    for (int t2 = 0; t2 < 2; ++t2) {
        int col = bn + wn + t2 * 16 + fr;
        if (col < N) {
            double bs = (double)bias[col];
#pragma unroll
            for (int r = 0; r < 4; ++r) {
                int row = bm + wm + 4 * g + r;
                size_t idx = (size_t)row * N + col;
                double v = (double)acc[t2][4][r];
                v = v * 256.0 + (double)acc[t2][3][r];
                v = v * 256.0 + (double)acc[t2][2][r];
                v = v * 256.0 + (double)acc[t2][1][r];
                v = v * 256.0 + (double)acc[t2][0][r];
                double cur = v * (L0 ? 0x1p-44 : 0x1p-40) + bs;
                double mp  = has_prev ? ms[t2][r] : 0.0;
                double rst = (mp > 1.0) ? 1.0 : 0.0;
                double mn  = 0.9 * mp + cur - rst;
                spk[idx] = (mn > 1.0) ? 1.0f : 0.0f;
                mem[idx] = (float)mn;
                ms[t2][r] = mn;
                if (spk_i8)
                    spk_i8[(size_t)row * 1024 + col] = (signed char)((mn > 1.0) ? 1 : 0);
            }
        }
    }
}

__global__ __launch_bounds__(512, 4) void snn_persist(Params P)
{
    const int bid  = blockIdx.x;
    const int wgid = (bid & 7) * 49 + (bid >> 3);   // bijective XCD remap (392=8*49)
    int layer, lid;
    if (wgid < 384) { layer = wgid >> 7; lid = wgid & 127; }
    else            { layer = 3;         lid = wgid - 384; }
    int bm, bn;
    if (layer == 3) { bm = lid * 64; bn = 0; }
    else            { bn = (lid >> 3) * 64; bm = (lid & 7) * 64; }

    const size_t LNH = (size_t)512 * 1000;
    const size_t LNO = (size_t)512 * 10;
    double ms[2][4] = {};

    for (int d = 0; d < 53; ++d) {
        int t = d - layer;
        if (t >= 0 && t < 50) {
            if (layer == 0) {
                run_tile<true>(P.xs + (size_t)t * 5 * 512 * 832, P.Wd[0], P.bias[0],
                               P.spk[0] + (size_t)t * LNH, P.mem[0] + (size_t)t * LNH,
                               P.sb[0][t & 1], (size_t)1024 * 832, 1000, bm, bn, t > 0, ms);
            } else if (layer == 1) {
                run_tile<false>(P.sb[0][t & 1], P.Wd[1], P.bias[1],
                                P.spk[1] + (size_t)t * LNH, P.mem[1] + (size_t)t * LNH,
                                P.sb[1][t & 1], (size_t)1024 * 1024, 1000, bm, bn, t > 0, ms);
            } else if (layer == 2) {
                run_tile<false>(P.sb[1][t & 1], P.Wd[2], P.bias[2],
                                P.spk[2] + (size_t)t * LNH, P.mem[2] + (size_t)t * LNH,
                                P.sb[2][t & 1], (size_t)1024 * 1024, 1000, bm, bn, t > 0, ms);
            } else {
                run_tile<false>(P.sb[2][t & 1], P.Wd[3], P.bias[3],
                                P.spk[3] + (size_t)t * LNO, P.mem[3] + (size_t)t * LNO,
                                nullptr, (size_t)64 * 1024, 10, bm, bn, t > 0, ms);
            }
        }
        if (d < 52) grid_barrier(P.bar);
    }
}

extern "C" void kernel_launch(void* const* d_in, const int* in_sizes, int n_in,
                              void* d_out, int out_size, void* d_ws, size_t ws_size,
                              hipStream_t stream)
{
    const float* x  = (const float*)d_in[0];
    const float* W0 = (const float*)d_in[1];
    const float* b0 = (const float*)d_in[2];
    const float* W1 = (const float*)d_in[3];
    const float* b1 = (const float*)d_in[4];
    const float* W2 = (const float*)d_in[5];
    const float* b2 = (const float*)d_in[6];
    const float* W3 = (const float*)d_in[7];
    const float* b3 = (const float*)d_in[8];
    float* out = (float*)d_out;

    const int T = 50;
    const size_t LNH = (size_t)512 * 1000;
    const size_t LNO = (size_t)512 * 10;

    float* spk0 = out;
    float* spk1 = spk0 + (size_t)T * LNH;
    float* spk2 = spk1 + (size_t)T * LNH;
    float* spk3 = spk2 + (size_t)T * LNH;
    float* mem0 = spk3 + (size_t)T * LNO;
    float* mem1 = mem0 + (size_t)T * LNH;
    float* mem2 = mem1 + (size_t)T * LNH;
    float* mem3 = mem2 + (size_t)T * LNH;

    // ---- workspace layout (all 16B-aligned) ----
    signed char* W0d = (signed char*)d_ws;                    // 5*1024*832
    signed char* W1d = W0d + (size_t)5 * 1024 * 832;          // 5*1024*1024
    signed char* W2d = W1d + (size_t)5 * 1024 * 1024;
    signed char* W3d = W2d + (size_t)5 * 1024 * 1024;         // 5*64*1024
    signed char* sbb = W3d + (size_t)5 * 64 * 1024;           // 6 x 512KB
    unsigned*    bar = (unsigned*)(sbb + (size_t)6 * 512 * 1024);
    signed char* xs  = (signed char*)bar + 256;               // 50*5*512*832

    // zero spike buffers (K-tail cols must stay 0) + barrier state
    hipMemsetAsync(sbb, 0, (size_t)6 * 512 * 1024 + 256, stream);

    // digit splits
    wsplit_i8<<<(1024 * 832  + 255) / 256, 256, 0, stream>>>(W0, W0d, 1000, 1024, 784,  832);
    wsplit_i8<<<(1024 * 1024 + 255) / 256, 256, 0, stream>>>(W1, W1d, 1000, 1024, 1000, 1024);
    wsplit_i8<<<(1024 * 1024 + 255) / 256, 256, 0, stream>>>(W2, W2d, 1000, 1024, 1000, 1024);
    wsplit_i8<<<(64 * 1024   + 255) / 256, 256, 0, stream>>>(W3, W3d, 10,   64,   1000, 1024);
    xsplit_i8<<<(50 * 512 * 832 + 255) / 256, 256, 0, stream>>>(x, xs);

    Params P;
    P.xs = xs;
    P.Wd[0] = W0d; P.Wd[1] = W1d; P.Wd[2] = W2d; P.Wd[3] = W3d;
    P.bias[0] = b0; P.bias[1] = b1; P.bias[2] = b2; P.bias[3] = b3;
    P.spk[0] = spk0; P.spk[1] = spk1; P.spk[2] = spk2; P.spk[3] = spk3;
    P.mem[0] = mem0; P.mem[1] = mem1; P.mem[2] = mem2; P.mem[3] = mem3;
    for (int ly = 0; ly < 3; ++ly)
        for (int pp = 0; pp < 2; ++pp)
            P.sb[ly][pp] = sbb + ((size_t)(ly * 2 + pp)) * 512 * 1024;
    P.bar = bar;

    snn_persist<<<NBLK, 512, 0, stream>>>(P);
}

// Round 7
// 10338.255 us; speedup vs baseline: 1.1212x; 1.1212x over previous
//
#include <hip/hip_runtime.h>

// SNN forward, exact fixed-point int8 MFMA, persistent kernel + grid barrier,
// LDS-staged inner loop (round-5 proven) with 1-deep register pipeline.
// Numerics identical to rounds 4/5/6 (all passed): spikes exact in i8; W = 5
// balanced base-256 digits of round(w*2^40); x pre-digitized to round(x*2^36);
// i32 MFMA accumulation exact; fp64 reconstruction (<2^53); membrane state in
// registers (fixed tile ownership). Spike i8 buffers double-buffered by t&1.

typedef int int4v __attribute__((ext_vector_type(4)));

#define XSCALE 68719476736.0      // 2^36
#define WSCALE 1099511627776.0    // 2^40
#define NBLK   392

struct Params {
    const signed char* xs;        // [50][5][512][832]
    const signed char* Wd[4];     // 5 planes each; rows padded to 1024/1024/1024/64
    const float* bias[4];
    float* spk[4];
    float* mem[4];
    signed char* sb[3][2];        // spike i8 buffers [layer][t&1], [512][1024]
    unsigned* bar;                // [counter, sense]
};

// ---- W digit split: fp32 [Nreal][K] -> 5 planes [Npad][Kpad], zero-padded ----
__global__ void wsplit_i8(const float* __restrict__ W, signed char* __restrict__ out,
                          int Nreal, int Npad, int K, int Kpad)
{
    int idx = blockIdx.x * blockDim.x + threadIdx.x;
    int total = Npad * Kpad;
    if (idx >= total) return;
    int n = idx / Kpad, k = idx - n * Kpad;
    long long v = 0;
    if (n < Nreal && k < K) v = __double2ll_rn((double)W[(size_t)n * K + k] * WSCALE);
    size_t plane = (size_t)total;
#pragma unroll
    for (int p = 0; p < 4; ++p) {
        int d = (int)(v & 255); if (d > 127) d -= 256;
        out[p * plane + idx] = (signed char)d;
        v = (v - d) >> 8;
    }
    out[4 * plane + idx] = (signed char)v;
}

// ---- x digit split: [50][512][784] -> [50][5][512][832] ----
__global__ void xsplit_i8(const float* __restrict__ x, signed char* __restrict__ out)
{
    const int RK = 512 * 832;
    int idx = blockIdx.x * blockDim.x + threadIdx.x;
    if (idx >= 50 * RK) return;
    int t = idx / RK, rem = idx - t * RK;
    int row = rem / 832, k = rem - row * 832;
    long long v = 0;
    if (k < 784) v = __double2ll_rn((double)x[((size_t)t * 512 + row) * 784 + k] * XSCALE);
    signed char* o = out + (size_t)t * 5 * RK + (size_t)row * 832 + k;
#pragma unroll
    for (int p = 0; p < 4; ++p) {
        int d = (int)(v & 255); if (d > 127) d -= 256;
        o[(size_t)p * RK] = (signed char)d;
        v = (v - d) >> 8;
    }
    o[(size_t)4 * RK] = (signed char)v;
}

// ---- device-scope sense-reversal grid barrier (validated round 6) ----
__device__ __forceinline__ void grid_barrier(unsigned* bar)
{
    __syncthreads();
    if (threadIdx.x == 0) {
        unsigned* cnt = bar;
        unsigned* sen = bar + 1;
        unsigned s0 = __hip_atomic_load(sen, __ATOMIC_RELAXED, __HIP_MEMORY_SCOPE_AGENT);
        unsigned a  = __hip_atomic_fetch_add(cnt, 1u, __ATOMIC_ACQ_REL, __HIP_MEMORY_SCOPE_AGENT);
        if (a == (unsigned)(NBLK - 1)) {
            __hip_atomic_store(cnt, 0u, __ATOMIC_RELAXED, __HIP_MEMORY_SCOPE_AGENT);
            __hip_atomic_fetch_add(sen, 1u, __ATOMIC_RELEASE, __HIP_MEMORY_SCOPE_AGENT);
        } else {
            while (__hip_atomic_load(sen, __ATOMIC_ACQUIRE, __HIP_MEMORY_SCOPE_AGENT) == s0)
                __builtin_amdgcn_s_sleep(2);
        }
    }
    __syncthreads();
}

// ---- one (layer,bm,bn) tile for one timestep: LDS-staged, reg-pipelined ----
template<bool L0>
__device__ __forceinline__ void run_tile(
    const signed char* __restrict__ Ap,    // A planes (xs[t] or spike buffer)
    const signed char* __restrict__ Wp,    // 5 padded W planes
    const float* __restrict__ bias,
    float* __restrict__ spk, float* __restrict__ mem,
    signed char* __restrict__ spk_i8,
    size_t planeA, size_t planeW, int N, int bm, int bn, bool has_prev,
    double (&ms)[2][4], signed char* Wld, signed char* Ald)
{
    constexpr int KP  = L0 ? 832 : 1024;
    constexpr int NIT = KP / 64;
    constexpr int NA  = L0 ? 5 : 1;

    const int tid = threadIdx.x;
    const int l  = tid & 63;
    const int w  = tid >> 6;           // 0..7
    const int wm = (w & 3) * 16;       // 0,16,32,48
    const int wn = (w >> 2) * 32;      // 0,32
    const int fr = l & 15;
    const int g  = l >> 4;             // 16B chunk select

    const int srow = tid >> 3;         // 0..63
    const int c8   = (tid & 7) * 8;    // 0..56

    const signed char* wg = Wp + (size_t)(bn + srow) * KP + c8;   // rows padded: no guard
    const signed char* ag = Ap + (size_t)(bm + srow) * KP + c8;

    // prologue: load k-block 0 into regs
    unsigned long long Wr[5], Ar[NA];
#pragma unroll
    for (int p = 0; p < 5; ++p) Wr[p] = *(const unsigned long long*)(wg + p * planeW);
#pragma unroll
    for (int p = 0; p < NA; ++p) Ar[p] = *(const unsigned long long*)(ag + p * planeA);

    int4v acc[2][5];
#pragma unroll
    for (int t2 = 0; t2 < 2; ++t2)
#pragma unroll
        for (int s = 0; s < 5; ++s) acc[t2][s] = (int4v){0, 0, 0, 0};

    for (int it = 0; it < NIT; ++it) {
        __syncthreads();               // all waves done reading prev k-block
#pragma unroll
        for (int p = 0; p < 5; ++p)
            *(unsigned long long*)&Wld[(p * 64 + srow) * 80 + c8] = Wr[p];
#pragma unroll
        for (int p = 0; p < NA; ++p)
            *(unsigned long long*)&Ald[(p * 64 + srow) * 80 + c8] = Ar[p];
        __syncthreads();               // k-block visible
        if (it + 1 < NIT) {            // issue next k-block loads; hide under compute
            int off = (it + 1) * 64;
#pragma unroll
            for (int p = 0; p < 5; ++p)
                Wr[p] = *(const unsigned long long*)(wg + p * planeW + off);
#pragma unroll
            for (int p = 0; p < NA; ++p)
                Ar[p] = *(const unsigned long long*)(ag + p * planeA + off);
        }
        int4v af[NA];
#pragma unroll
        for (int p = 0; p < NA; ++p)
            af[p] = *(const int4v*)&Ald[(p * 64 + wm + fr) * 80 + 16 * g];
#pragma unroll
        for (int t2 = 0; t2 < 2; ++t2) {
#pragma unroll
            for (int q = 0; q < 5; ++q) {
                int4v bq = *(const int4v*)&Wld[(q * 64 + wn + t2 * 16 + fr) * 80 + 16 * g];
                if constexpr (L0) {
#pragma unroll
                    for (int p = 0; p < 5; ++p)
                        if (p + q >= 4)
                            acc[t2][p + q - 4] = __builtin_amdgcn_mfma_i32_16x16x64_i8(
                                af[p], bq, acc[t2][p + q - 4], 0, 0, 0);
                } else {
                    acc[t2][q] = __builtin_amdgcn_mfma_i32_16x16x64_i8(
                        af[0], bq, acc[t2][q], 0, 0, 0);
                }
            }
        }
    }

    // epilogue: fp64 reconstruction + leaky-IF; C/D: col=l&15, row=4*(l>>4)+r
#pragma unroll
    for (int t2 = 0; t2 < 2; ++t2) {
        int col = bn + wn + t2 * 16 + fr;
        if (col < N) {
            double bs = (double)bias[col];
#pragma unroll
            for (int r = 0; r < 4; ++r) {
                int row = bm + wm + 4 * g + r;
                size_t idx = (size_t)row * N + col;
                double v = (double)acc[t2][4][r];
                v = v * 256.0 + (double)acc[t2][3][r];
                v = v * 256.0 + (double)acc[t2][2][r];
                v = v * 256.0 + (double)acc[t2][1][r];
                v = v * 256.0 + (double)acc[t2][0][r];
                double cur = v * (L0 ? 0x1p-44 : 0x1p-40) + bs;
                double mp  = has_prev ? ms[t2][r] : 0.0;
                double rst = (mp > 1.0) ? 1.0 : 0.0;
                double mn  = 0.9 * mp + cur - rst;
                spk[idx] = (mn > 1.0) ? 1.0f : 0.0f;
                mem[idx] = (float)mn;
                ms[t2][r] = mn;
                if (spk_i8)
                    spk_i8[(size_t)row * 1024 + col] = (signed char)((mn > 1.0) ? 1 : 0);
            }
        }
    }
}

__global__ __launch_bounds__(512, 4) void snn_persist(Params P)
{
    __shared__ __align__(16) signed char Wld[5 * 64 * 80];   // 25.6 KB
    __shared__ __align__(16) signed char Ald[5 * 64 * 80];   // 25.6 KB (L0; else 5KB used)

    const int bid  = blockIdx.x;
    const int wgid = (bid & 7) * 49 + (bid >> 3);   // bijective XCD remap (392=8*49)
    int layer, lid;
    if (wgid < 384) { layer = wgid >> 7; lid = wgid & 127; }
    else            { layer = 3;         lid = wgid - 384; }
    int bm, bn;
    if (layer == 3) { bm = lid * 64; bn = 0; }
    else            { bn = (lid >> 3) * 64; bm = (lid & 7) * 64; }

    const size_t LNH = (size_t)512 * 1000;
    const size_t LNO = (size_t)512 * 10;
    const size_t RK  = (size_t)512 * 832;
    double ms[2][4] = {};

    for (int d = 0; d < 53; ++d) {
        int t = d - layer;
        if (t >= 0 && t < 50) {
            if (layer == 0) {
                run_tile<true>(P.xs + (size_t)t * 5 * RK, P.Wd[0], P.bias[0],
                               P.spk[0] + (size_t)t * LNH, P.mem[0] + (size_t)t * LNH,
                               P.sb[0][t & 1], RK, (size_t)1024 * 832,
                               1000, bm, bn, t > 0, ms, Wld, Ald);
            } else if (layer == 1) {
                run_tile<false>(P.sb[0][t & 1], P.Wd[1], P.bias[1],
                                P.spk[1] + (size_t)t * LNH, P.mem[1] + (size_t)t * LNH,
                                P.sb[1][t & 1], 0, (size_t)1024 * 1024,
                                1000, bm, bn, t > 0, ms, Wld, Ald);
            } else if (layer == 2) {
                run_tile<false>(P.sb[1][t & 1], P.Wd[2], P.bias[2],
                                P.spk[2] + (size_t)t * LNH, P.mem[2] + (size_t)t * LNH,
                                P.sb[2][t & 1], 0, (size_t)1024 * 1024,
                                1000, bm, bn, t > 0, ms, Wld, Ald);
            } else {
                run_tile<false>(P.sb[2][t & 1], P.Wd[3], P.bias[3],
                                P.spk[3] + (size_t)t * LNO, P.mem[3] + (size_t)t * LNO,
                                nullptr, 0, (size_t)64 * 1024,
                                10, bm, bn, t > 0, ms, Wld, Ald);
            }
        }
        if (d < 52) grid_barrier(P.bar);
    }
}

extern "C" void kernel_launch(void* const* d_in, const int* in_sizes, int n_in,
                              void* d_out, int out_size, void* d_ws, size_t ws_size,
                              hipStream_t stream)
{
    const float* x  = (const float*)d_in[0];
    const float* W0 = (const float*)d_in[1];
    const float* b0 = (const float*)d_in[2];
    const float* W1 = (const float*)d_in[3];
    const float* b1 = (const float*)d_in[4];
    const float* W2 = (const float*)d_in[5];
    const float* b2 = (const float*)d_in[6];
    const float* W3 = (const float*)d_in[7];
    const float* b3 = (const float*)d_in[8];
    float* out = (float*)d_out;

    const int T = 50;
    const size_t LNH = (size_t)512 * 1000;
    const size_t LNO = (size_t)512 * 10;

    float* spk0 = out;
    float* spk1 = spk0 + (size_t)T * LNH;
    float* spk2 = spk1 + (size_t)T * LNH;
    float* spk3 = spk2 + (size_t)T * LNH;
    float* mem0 = spk3 + (size_t)T * LNO;
    float* mem1 = mem0 + (size_t)T * LNH;
    float* mem2 = mem1 + (size_t)T * LNH;
    float* mem3 = mem2 + (size_t)T * LNH;

    // ---- workspace layout (all 16B-aligned) ----
    signed char* W0d = (signed char*)d_ws;                    // 5*1024*832
    signed char* W1d = W0d + (size_t)5 * 1024 * 832;          // 5*1024*1024
    signed char* W2d = W1d + (size_t)5 * 1024 * 1024;
    signed char* W3d = W2d + (size_t)5 * 1024 * 1024;         // 5*64*1024
    signed char* sbb = W3d + (size_t)5 * 64 * 1024;           // 6 x 512KB
    unsigned*    bar = (unsigned*)(sbb + (size_t)6 * 512 * 1024);
    signed char* xs  = (signed char*)bar + 256;               // 50*5*512*832

    // zero spike buffers (K-tail cols must stay 0) + barrier state
    hipMemsetAsync(sbb, 0, (size_t)6 * 512 * 1024 + 256, stream);

    // digit splits
    wsplit_i8<<<(1024 * 832  + 255) / 256, 256, 0, stream>>>(W0, W0d, 1000, 1024, 784,  832);
    wsplit_i8<<<(1024 * 1024 + 255) / 256, 256, 0, stream>>>(W1, W1d, 1000, 1024, 1000, 1024);
    wsplit_i8<<<(1024 * 1024 + 255) / 256, 256, 0, stream>>>(W2, W2d, 1000, 1024, 1000, 1024);
    wsplit_i8<<<(64 * 1024   + 255) / 256, 256, 0, stream>>>(W3, W3d, 10,   64,   1000, 1024);
    xsplit_i8<<<(50 * 512 * 832 + 255) / 256, 256, 0, stream>>>(x, xs);

    Params P;
    P.xs = xs;
    P.Wd[0] = W0d; P.Wd[1] = W1d; P.Wd[2] = W2d; P.Wd[3] = W3d;
    P.bias[0] = b0; P.bias[1] = b1; P.bias[2] = b2; P.bias[3] = b3;
    P.spk[0] = spk0; P.spk[1] = spk1; P.spk[2] = spk2; P.spk[3] = spk3;
    P.mem[0] = mem0; P.mem[1] = mem1; P.mem[2] = mem2; P.mem[3] = mem3;
    for (int ly = 0; ly < 3; ++ly)
        for (int pp = 0; pp < 2; ++pp)
            P.sb[ly][pp] = sbb + ((size_t)(ly * 2 + pp)) * 512 * 1024;
    P.bar = bar;

    snn_persist<<<NBLK, 512, 0, stream>>>(P);
}

// Round 8
// 1325.950 us; speedup vs baseline: 8.7416x; 7.7969x over previous
//
#include <hip/hip_runtime.h>

// SNN forward, exact fixed-point int8 MFMA, DECOUPLED structure:
//   cur(l,t) = spk(l-1,t) @ W_l  -- no membrane dependence -> batched GEMM over
//   a chunk of TC=10 timesteps (M=5120), fully parallel, no barriers/atomics.
//   Leaky-IF t-recursion lives only in a cheap elementwise kernel (state in regs).
// Numerics identical to rounds 4-7 (all passed): spikes exact in i8; W = 5
// balanced base-256 digits of round(w*2^40); x digitized to round(x*2^36);
// i32 MFMA accumulation exact; cur stored as fp64 (<2^53, exact, pow2 scale);
// IF chain in fp64.

typedef int int4v __attribute__((ext_vector_type(4)));

#define XSCALE 68719476736.0      // 2^36
#define WSCALE 1099511627776.0    // 2^40
#define TC 10                     // timestep chunk

// ---- W digit split: fp32 [Nreal][K] -> 5 planes [Npad][Kpad], zero-padded ----
__global__ void wsplit_i8(const float* __restrict__ W, signed char* __restrict__ out,
                          int Nreal, int Npad, int K, int Kpad)
{
    int idx = blockIdx.x * blockDim.x + threadIdx.x;
    int total = Npad * Kpad;
    if (idx >= total) return;
    int n = idx / Kpad, k = idx - n * Kpad;
    long long v = 0;
    if (n < Nreal && k < K) v = __double2ll_rn((double)W[(size_t)n * K + k] * WSCALE);
    size_t plane = (size_t)total;
#pragma unroll
    for (int p = 0; p < 4; ++p) {
        int d = (int)(v & 255); if (d > 127) d -= 256;
        out[p * plane + idx] = (signed char)d;
        v = (v - d) >> 8;
    }
    out[4 * plane + idx] = (signed char)v;
}

// ---- x chunk digitize: [TC*512][784] fp32 -> 5 planes [5120][832] ----
__global__ void xsplit_chunk(const float* __restrict__ x, signed char* __restrict__ out)
{
    int idx = blockIdx.x * blockDim.x + threadIdx.x;
    if (idx >= 5120 * 832) return;
    int row = idx / 832, k = idx - row * 832;
    long long v = 0;
    if (k < 784) v = __double2ll_rn((double)x[(size_t)row * 784 + k] * XSCALE);
    const size_t plane = (size_t)5120 * 832;
    signed char* o = out + idx;
#pragma unroll
    for (int p = 0; p < 4; ++p) {
        int d = (int)(v & 255); if (d > 127) d -= 256;
        o[p * plane] = (signed char)d;
        v = (v - d) >> 8;
    }
    o[4 * plane] = (signed char)v;
}

// ---- chunk GEMM: cur[M=5120][1024-strided] (fp64) = A @ W^T, exact ----
// BN: 64 or 128. NA: A digit planes (5 for layer 0, 1 for spikes).
// Block 512 thr = 8 waves; tile 64(M) x BN(N); wave tile 16 x BN/2.
template<int BN, int NA, int KP>
__global__ __launch_bounds__(512)
void gemm_cur(const signed char* __restrict__ Ap, size_t planeA,
              const signed char* __restrict__ Wp, size_t planeW,
              double* __restrict__ curout, int N)
{
    __shared__ __align__(16) signed char Wld[5 * BN * 80];
    __shared__ __align__(16) signed char Ald[NA * 64 * 80];
    constexpr int NIT = KP / 64;
    constexpr int NT2 = BN / 32;

    const int tid = threadIdx.x;
    const int l  = tid & 63;
    const int w  = tid >> 6;
    const int wm = (w & 3) * 16;
    const int wn = (w >> 2) * (BN / 2);
    const int fr = l & 15;
    const int g  = l >> 4;
    const int bm = blockIdx.y * 64;
    const int bn = blockIdx.x * BN;

    // staging: A = 64 rows x 64B (u64/thread/plane); W rows padded, guard-free
    const int srow = tid >> 3;                      // 0..63
    const int c8   = (tid & 7) * 8;
    const signed char* ag = Ap + (size_t)(bm + srow) * KP + c8;

    unsigned long long Ar[NA];
#pragma unroll
    for (int p = 0; p < NA; ++p) Ar[p] = *(const unsigned long long*)(ag + p * planeA);

    int4v acc[NT2][5];
#pragma unroll
    for (int t2 = 0; t2 < NT2; ++t2)
#pragma unroll
        for (int s = 0; s < 5; ++s) acc[t2][s] = (int4v){0, 0, 0, 0};

    if constexpr (BN == 64) {
        const signed char* wg = Wp + (size_t)(bn + srow) * KP + c8;
        unsigned long long Wr[5];
#pragma unroll
        for (int p = 0; p < 5; ++p) Wr[p] = *(const unsigned long long*)(wg + p * planeW);

        for (int it = 0; it < NIT; ++it) {
            __syncthreads();
#pragma unroll
            for (int p = 0; p < 5; ++p)
                *(unsigned long long*)&Wld[(p * 64 + srow) * 80 + c8] = Wr[p];
#pragma unroll
            for (int p = 0; p < NA; ++p)
                *(unsigned long long*)&Ald[(p * 64 + srow) * 80 + c8] = Ar[p];
            __syncthreads();
            if (it + 1 < NIT) {
                int off = (it + 1) * 64;
#pragma unroll
                for (int p = 0; p < 5; ++p)
                    Wr[p] = *(const unsigned long long*)(wg + p * planeW + off);
#pragma unroll
                for (int p = 0; p < NA; ++p)
                    Ar[p] = *(const unsigned long long*)(ag + p * planeA + off);
            }
            int4v af[NA];
#pragma unroll
            for (int p = 0; p < NA; ++p)
                af[p] = *(const int4v*)&Ald[(p * 64 + wm + fr) * 80 + 16 * g];
#pragma unroll
            for (int t2 = 0; t2 < NT2; ++t2) {
#pragma unroll
                for (int q = 0; q < 5; ++q) {
                    int4v bq = *(const int4v*)&Wld[(q * 64 + wn + t2 * 16 + fr) * 80 + 16 * g];
                    if constexpr (NA == 5) {
#pragma unroll
                        for (int p = 0; p < 5; ++p)
                            if (p + q >= 4)
                                acc[t2][p + q - 4] = __builtin_amdgcn_mfma_i32_16x16x64_i8(
                                    af[p], bq, acc[t2][p + q - 4], 0, 0, 0);
                    } else {
                        acc[t2][q] = __builtin_amdgcn_mfma_i32_16x16x64_i8(
                            af[0], bq, acc[t2][q], 0, 0, 0);
                    }
                }
            }
        }
    } else {  // BN == 128
        const int wrow = tid >> 2;                  // 0..127
        const int wc   = (tid & 3) * 16;
        const signed char* wg = Wp + (size_t)(bn + wrow) * KP + wc;
        int4v Wr[5];
#pragma unroll
        for (int p = 0; p < 5; ++p) Wr[p] = *(const int4v*)(wg + p * planeW);

        for (int it = 0; it < NIT; ++it) {
            __syncthreads();
#pragma unroll
            for (int p = 0; p < 5; ++p)
                *(int4v*)&Wld[(p * 128 + wrow) * 80 + wc] = Wr[p];
#pragma unroll
            for (int p = 0; p < NA; ++p)
                *(unsigned long long*)&Ald[(p * 64 + srow) * 80 + c8] = Ar[p];
            __syncthreads();
            if (it + 1 < NIT) {
                int off = (it + 1) * 64;
#pragma unroll
                for (int p = 0; p < 5; ++p)
                    Wr[p] = *(const int4v*)(wg + p * planeW + off);
#pragma unroll
                for (int p = 0; p < NA; ++p)
                    Ar[p] = *(const unsigned long long*)(ag + p * planeA + off);
            }
            int4v af[NA];
#pragma unroll
            for (int p = 0; p < NA; ++p)
                af[p] = *(const int4v*)&Ald[(p * 64 + wm + fr) * 80 + 16 * g];
#pragma unroll
            for (int t2 = 0; t2 < NT2; ++t2) {
#pragma unroll
                for (int q = 0; q < 5; ++q) {
                    int4v bq = *(const int4v*)&Wld[(q * 128 + wn + t2 * 16 + fr) * 80 + 16 * g];
                    acc[t2][q] = __builtin_amdgcn_mfma_i32_16x16x64_i8(
                        af[0], bq, acc[t2][q], 0, 0, 0);
                }
            }
        }
    }

    // epilogue: exact fp64 reconstruction; C/D: col=l&15, row=4*(l>>4)+r
    const double scale = (NA == 5) ? 0x1p-44 : 0x1p-40;
#pragma unroll
    for (int t2 = 0; t2 < NT2; ++t2) {
        int col = bn + wn + t2 * 16 + fr;
        if (col < N) {
#pragma unroll
            for (int r = 0; r < 4; ++r) {
                int m = bm + wm + 4 * g + r;
                double v = (double)acc[t2][4][r];
                v = v * 256.0 + (double)acc[t2][3][r];
                v = v * 256.0 + (double)acc[t2][2][r];
                v = v * 256.0 + (double)acc[t2][1][r];
                v = v * 256.0 + (double)acc[t2][0][r];
                curout[(size_t)m * 1024 + col] = v * scale;
            }
        }
    }
}

// ---- elementwise leaky-IF over a chunk: one thread per neuron, t in regs ----
__global__ __launch_bounds__(256)
void if_update(const double* __restrict__ cur, const float* __restrict__ bias,
               double* __restrict__ mw, float* __restrict__ spk,
               float* __restrict__ mem, signed char* __restrict__ spk_i8,
               int N, int first)
{
    int idx = blockIdx.x * blockDim.x + threadIdx.x;
    if (idx >= 512 * N) return;
    int row = idx / N, col = idx - row * N;
    double mp = first ? 0.0 : mw[idx];
    double bs = (double)bias[col];
#pragma unroll 2
    for (int t = 0; t < TC; ++t) {
        double c   = cur[((size_t)t * 512 + row) * 1024 + col] + bs;
        double rst = (mp > 1.0) ? 1.0 : 0.0;
        double mn  = 0.9 * mp + c - rst;
        size_t o   = ((size_t)t * 512 + row) * N + col;
        spk[o] = (mn > 1.0) ? 1.0f : 0.0f;
        mem[o] = (float)mn;
        if (spk_i8)
            spk_i8[((size_t)t * 512 + row) * 1024 + col] = (signed char)((mn > 1.0) ? 1 : 0);
        mp = mn;
    }
    mw[idx] = mp;
}

extern "C" void kernel_launch(void* const* d_in, const int* in_sizes, int n_in,
                              void* d_out, int out_size, void* d_ws, size_t ws_size,
                              hipStream_t stream)
{
    const float* x  = (const float*)d_in[0];
    const float* W0 = (const float*)d_in[1];
    const float* b0 = (const float*)d_in[2];
    const float* W1 = (const float*)d_in[3];
    const float* b1 = (const float*)d_in[4];
    const float* W2 = (const float*)d_in[5];
    const float* b2 = (const float*)d_in[6];
    const float* W3 = (const float*)d_in[7];
    const float* b3 = (const float*)d_in[8];
    float* out = (float*)d_out;

    const int T = 50;
    const size_t LNH = (size_t)512 * 1000;
    const size_t LNO = (size_t)512 * 10;

    float* spk0 = out;
    float* spk1 = spk0 + (size_t)T * LNH;
    float* spk2 = spk1 + (size_t)T * LNH;
    float* spk3 = spk2 + (size_t)T * LNH;
    float* mem0 = spk3 + (size_t)T * LNO;
    float* mem1 = mem0 + (size_t)T * LNH;
    float* mem2 = mem1 + (size_t)T * LNH;
    float* mem3 = mem2 + (size_t)T * LNH;

    // ---- workspace layout: fp64 regions first, then i8 ----
    double* cur = (double*)d_ws;                          // 5120*1024*8 = 41.9 MB
    double* mw0 = cur + (size_t)5120 * 1024;
    double* mw1 = mw0 + LNH;
    double* mw2 = mw1 + LNH;
    double* mw3 = mw2 + LNH;                              // +10 KB
    signed char* W0d = (signed char*)(mw3 + LNO);         // 5*1024*832
    signed char* W1d = W0d + (size_t)5 * 1024 * 832;      // 5*1024*1024
    signed char* W2d = W1d + (size_t)5 * 1024 * 1024;
    signed char* W3d = W2d + (size_t)5 * 1024 * 1024;     // 5*64*1024
    signed char* xsb = W3d + (size_t)5 * 64 * 1024;       // 5*5120*832 = 21.3 MB
    signed char* sp0 = xsb + (size_t)5 * 5120 * 832;      // 5120*1024 each
    signed char* sp1 = sp0 + (size_t)5120 * 1024;
    signed char* sp2 = sp1 + (size_t)5120 * 1024;

    // zero spike chunk buffers once (K-tail cols 1000..1023 must stay 0)
    hipMemsetAsync(sp0, 0, (size_t)3 * 5120 * 1024, stream);

    // W digit splits (once per call)
    wsplit_i8<<<(1024 * 832  + 255) / 256, 256, 0, stream>>>(W0, W0d, 1000, 1024, 784,  832);
    wsplit_i8<<<(1024 * 1024 + 255) / 256, 256, 0, stream>>>(W1, W1d, 1000, 1024, 1000, 1024);
    wsplit_i8<<<(1024 * 1024 + 255) / 256, 256, 0, stream>>>(W2, W2d, 1000, 1024, 1000, 1024);
    wsplit_i8<<<(64 * 1024   + 255) / 256, 256, 0, stream>>>(W3, W3d, 10,   64,   1000, 1024);

    const size_t plA0 = (size_t)5120 * 832;
    const size_t plW0 = (size_t)1024 * 832;
    const size_t plWH = (size_t)1024 * 1024;
    const size_t plW3 = (size_t)64 * 1024;

    dim3 blk(512);
    dim3 g0(16, 80), gH(8, 80), g3(1, 80);

    for (int c = 0; c < T / TC; ++c) {
        const int t0 = c * TC;
        const int first = (c == 0);

        xsplit_chunk<<<(5120 * 832 + 255) / 256, 256, 0, stream>>>(
            x + (size_t)t0 * 512 * 784, xsb);

        gemm_cur<64, 5, 832><<<g0, blk, 0, stream>>>(xsb, plA0, W0d, plW0, cur, 1000);
        if_update<<<2000, 256, 0, stream>>>(cur, b0, mw0,
            spk0 + (size_t)t0 * LNH, mem0 + (size_t)t0 * LNH, sp0, 1000, first);

        gemm_cur<128, 1, 1024><<<gH, blk, 0, stream>>>(sp0, 0, W1d, plWH, cur, 1000);
        if_update<<<2000, 256, 0, stream>>>(cur, b1, mw1,
            spk1 + (size_t)t0 * LNH, mem1 + (size_t)t0 * LNH, sp1, 1000, first);

        gemm_cur<128, 1, 1024><<<gH, blk, 0, stream>>>(sp1, 0, W2d, plWH, cur, 1000);
        if_update<<<2000, 256, 0, stream>>>(cur, b2, mw2,
            spk2 + (size_t)t0 * LNH, mem2 + (size_t)t0 * LNH, sp2, 1000, first);

        gemm_cur<64, 1, 1024><<<g3, blk, 0, stream>>>(sp2, 0, W3d, plW3, cur, 10);
        if_update<<<20, 256, 0, stream>>>(cur, b3, mw3,
            spk3 + (size_t)t0 * LNO, mem3 + (size_t)t0 * LNO, nullptr, 10, first);
    }
}